// Round 1
// 7619.473 us; speedup vs baseline: 1.8998x; 1.8998x over previous
//
#include <hip/hip_runtime.h>
#include <math.h>

#define NN 1024     // nodes
#define BB 64       // batch
#define DD 10       // embedding dim
#define TT 12       // timesteps

typedef __attribute__((ext_vector_type(8))) short bf16x8;
typedef __attribute__((ext_vector_type(8))) unsigned short ushort8;
typedef __attribute__((ext_vector_type(4))) float f32x4;

__device__ inline unsigned short bf16_rne(float x) {
  unsigned u = __float_as_uint(x);
  return (unsigned short)((u + 0x7FFFu + ((u >> 16) & 1u)) >> 16);
}
__device__ inline void split2(float x, unsigned short& h, unsigned short& l) {
  unsigned short hh = bf16_rne(x);
  h = hh;
  l = bf16_rne(x - __uint_as_float((unsigned)hh << 16));
}

// global -> LDS async 16B/lane (LDS dest = wave-uniform base + lane*16)
#define GLOAD16(gp, lp)                                                        \
  __builtin_amdgcn_global_load_lds(                                            \
      (const __attribute__((address_space(1))) unsigned int*)(gp),             \
      (__attribute__((address_space(3))) unsigned int*)(lp), 16, 0, 0)

// ---------------------------------------------------------------------------
// A = softmax(relu(E @ E^T), axis=1)   one block per row n
// ---------------------------------------------------------------------------
__global__ __launch_bounds__(256) void build_A(const float* __restrict__ E,
                                               float* __restrict__ A) {
  __shared__ float row[NN];
  __shared__ float red[256];
  int n = blockIdx.x;
  float e[DD];
#pragma unroll
  for (int d = 0; d < DD; d++) e[d] = E[n * DD + d];
  float mx = -1e30f;
  for (int m = threadIdx.x; m < NN; m += 256) {
    float s = 0.f;
#pragma unroll
    for (int d = 0; d < DD; d++) s += e[d] * E[m * DD + d];
    s = fmaxf(s, 0.f);
    row[m] = s;
    mx = fmaxf(mx, s);
  }
  red[threadIdx.x] = mx;
  __syncthreads();
  for (int w = 128; w > 0; w >>= 1) {
    if (threadIdx.x < w) red[threadIdx.x] = fmaxf(red[threadIdx.x], red[threadIdx.x + w]);
    __syncthreads();
  }
  mx = red[0];
  __syncthreads();
  float sum = 0.f;
  for (int m = threadIdx.x; m < NN; m += 256) {
    float v = expf(row[m] - mx);
    row[m] = v;
    sum += v;
  }
  red[threadIdx.x] = sum;
  __syncthreads();
  for (int w = 128; w > 0; w >>= 1) {
    if (threadIdx.x < w) red[threadIdx.x] += red[threadIdx.x + w];
    __syncthreads();
  }
  float inv = 1.f / red[0];
  for (int m = threadIdx.x; m < NN; m += 256) A[n * NN + m] = row[m] * inv;
}

// ---------------------------------------------------------------------------
// split fp32 [1024][1024] -> bf16 hi/lo (same layout, row-major, K-contig)
// ---------------------------------------------------------------------------
__global__ __launch_bounds__(256) void split_bf16(const float* __restrict__ S,
                                                  unsigned short* __restrict__ H,
                                                  unsigned short* __restrict__ L) {
  int idx = blockIdx.x * 256 + threadIdx.x;  // 131072 tasks of 8
  size_t o = (size_t)idx * 8;
  ushort8 hv, lv;
#pragma unroll
  for (int j = 0; j < 8; j++) {
    unsigned short hh, ll;
    split2(S[o + j], hh, ll);
    hv[j] = hh; lv[j] = ll;
  }
  *(ushort8*)&H[o] = hv;
  *(ushort8*)&L[o] = lv;
}

// ---------------------------------------------------------------------------
// transpose + split:  X fp32 [1024][F]  ->  Th/Tl bf16 [F][1024]
// tile 64 n-rows x 128 f-cols per block
// ---------------------------------------------------------------------------
__global__ __launch_bounds__(256) void txsplit(const float* __restrict__ X,
                                               unsigned short* __restrict__ Th,
                                               unsigned short* __restrict__ Tl,
                                               int F) {
  __shared__ float tile[64][129];  // pad 129: phase-2 column reads conflict-free
  int f0 = blockIdx.x * 128, n0 = blockIdx.y * 64;
  int tid = threadIdx.x;
#pragma unroll
  for (int r = 0; r < 8; r++) {
    int idx = tid + r * 256;
    int row = idx >> 5, c4 = (idx & 31) << 2;
    float4 v = *(const float4*)&X[(size_t)(n0 + row) * F + f0 + c4];
    tile[row][c4 + 0] = v.x; tile[row][c4 + 1] = v.y;
    tile[row][c4 + 2] = v.z; tile[row][c4 + 3] = v.w;
  }
  __syncthreads();
#pragma unroll
  for (int r = 0; r < 4; r++) {
    int t = tid + r * 256;
    int f = t >> 3, c8 = (t & 7) << 3;
    ushort8 hv, lv;
#pragma unroll
    for (int j = 0; j < 8; j++) {
      unsigned short hh, ll;
      split2(tile[c8 + j][f], hh, ll);
      hv[j] = hh; lv[j] = ll;
    }
    size_t o = (size_t)(f0 + f) * NN + n0 + c8;
    *(ushort8*)&Th[o] = hv;
    *(ushort8*)&Tl[o] = lv;
  }
}

// ---------------------------------------------------------------------------
// MFMA split-bf16 GEMM:  Y[1024][F] = S[1024][1024] @ X[1024][F]
//   S given as hi/lo bf16 [m][k] row-major (K-contig);
//   X given as hi/lo bf16 TRANSPOSED [f][k] (K-contig);
//   Y += via 3 products: Sh@Xh + Sl@Xh + Sh@Xl  (fp32 accum).
// Tile 128x128, BK=32, 4 waves (2x2), 16x16x32 mfma, 4x4 frags/wave.
// LDS: row-pair packed [64 rowpairs][128B] with XOR-8 slot swizzle,
// staged by global_load_lds with pre-swizzled per-lane source addresses.
// Double-buffered, one barrier per K-step.  Up to 2 fused ops via blockIdx.z.
// ---------------------------------------------------------------------------
__global__ __launch_bounds__(256) void gemm_mfma(
    const unsigned short* __restrict__ A0h, const unsigned short* __restrict__ A0l,
    const unsigned short* __restrict__ X0h, const unsigned short* __restrict__ X0l,
    float* __restrict__ Y0,
    const unsigned short* __restrict__ A1h, const unsigned short* __restrict__ A1l,
    const unsigned short* __restrict__ X1h, const unsigned short* __restrict__ X1l,
    float* __restrict__ Y1,
    int F) {
  const unsigned short* Sh = blockIdx.z ? A1h : A0h;
  const unsigned short* Sl = blockIdx.z ? A1l : A0l;
  const unsigned short* Xh = blockIdx.z ? X1h : X0h;
  const unsigned short* Xl = blockIdx.z ? X1l : X0l;
  float* Y = blockIdx.z ? Y1 : Y0;

  __shared__ unsigned short lds[2][4][4096] __attribute__((aligned(16)));  // [buf][Sh,Sl,Xh,Xl][8KB]
  int tid = threadIdx.x;
  int lane = tid & 63, wave = tid >> 6;
  int m0 = blockIdx.y * 128, f0 = blockIdx.x * 128;

  // ---- staging geometry: chunk i = rep*256 + wave*64 + lane (16B each) ----
  // rp = i>>3 (row pair), ss = lane&7 (swizzled slot), sl = ss ^ (rp&7)
  int sl = (lane & 7) ^ (lane >> 3);
  int hp = sl >> 2, s4 = sl & 3;
  int rp0 = wave * 8 + (lane >> 3);          // rep 0: rp 0..31 -> rows 0..63
  int rowR0 = 2 * rp0 + hp;
  int rowR1 = 2 * (rp0 + 32) + hp;           // rep 1: rows 64..127
  int kcol = s4 * 8;                          // k element offset 0..24

  const unsigned short* gS0 = Sh + (size_t)(m0 + rowR0) * NN + kcol;
  const unsigned short* gS1 = Sh + (size_t)(m0 + rowR1) * NN + kcol;
  const unsigned short* gT0 = Sl + (size_t)(m0 + rowR0) * NN + kcol;
  const unsigned short* gT1 = Sl + (size_t)(m0 + rowR1) * NN + kcol;
  const unsigned short* gU0 = Xh + (size_t)(f0 + rowR0) * NN + kcol;
  const unsigned short* gU1 = Xh + (size_t)(f0 + rowR1) * NN + kcol;
  const unsigned short* gV0 = Xl + (size_t)(f0 + rowR0) * NN + kcol;
  const unsigned short* gV1 = Xl + (size_t)(f0 + rowR1) * NN + kcol;

#define STAGE(buf, k0)                                   \
  {                                                      \
    unsigned short(*L)[4096] = lds[buf];                 \
    int w512 = wave * 512;                               \
    GLOAD16(gS0 + (k0), &L[0][w512]);                    \
    GLOAD16(gS1 + (k0), &L[0][2048 + w512]);             \
    GLOAD16(gT0 + (k0), &L[1][w512]);                    \
    GLOAD16(gT1 + (k0), &L[1][2048 + w512]);             \
    GLOAD16(gU0 + (k0), &L[2][w512]);                    \
    GLOAD16(gU1 + (k0), &L[2][2048 + w512]);             \
    GLOAD16(gV0 + (k0), &L[3][w512]);                    \
    GLOAD16(gV1 + (k0), &L[3][2048 + w512]);             \
  }

  // ---- per-thread fragment read offsets (bytes within one 8KB matrix) ----
  int offA[4], offX[4];
#pragma unroll
  for (int q = 0; q < 4; q++) {
    int r = (wave >> 1) * 64 + q * 16 + (lane & 15);
    offA[q] = (r >> 1) * 128 +
              ((((((r & 1) << 2) | (lane >> 4)) ^ ((r >> 1) & 7))) << 4);
    int rx = (wave & 1) * 64 + q * 16 + (lane & 15);
    offX[q] = (rx >> 1) * 128 +
              ((((((rx & 1) << 2) | (lane >> 4)) ^ ((rx >> 1) & 7))) << 4);
  }

  f32x4 acc[4][4];
  f32x4 zz = {0.f, 0.f, 0.f, 0.f};
#pragma unroll
  for (int i = 0; i < 4; i++)
#pragma unroll
    for (int j = 0; j < 4; j++) acc[i][j] = zz;

  STAGE(0, 0);
  __syncthreads();

  for (int it = 0; it < 32; ++it) {
    int buf = it & 1;
    if (it < 31) STAGE(buf ^ 1, (it + 1) * 32);
    const char* base = (const char*)lds[buf];
    bf16x8 ah[4], al[4], xh[4], xl[4];
#pragma unroll
    for (int q = 0; q < 4; q++) {
      ah[q] = *(const bf16x8*)(base + offA[q]);
      al[q] = *(const bf16x8*)(base + 8192 + offA[q]);
      xh[q] = *(const bf16x8*)(base + 16384 + offX[q]);
      xl[q] = *(const bf16x8*)(base + 24576 + offX[q]);
    }
#pragma unroll
    for (int i = 0; i < 4; i++)
#pragma unroll
      for (int j = 0; j < 4; j++) {
        acc[i][j] = __builtin_amdgcn_mfma_f32_16x16x32_bf16(ah[i], xh[j], acc[i][j], 0, 0, 0);
        acc[i][j] = __builtin_amdgcn_mfma_f32_16x16x32_bf16(al[i], xh[j], acc[i][j], 0, 0, 0);
        acc[i][j] = __builtin_amdgcn_mfma_f32_16x16x32_bf16(ah[i], xl[j], acc[i][j], 0, 0, 0);
      }
    __syncthreads();
  }
#undef STAGE

  // ---- epilogue: D lane map col=lane&15, row=(lane>>4)*4+reg ----
  int r0 = m0 + (wave >> 1) * 64 + ((lane >> 4) << 2);
  int c0 = f0 + (wave & 1) * 64 + (lane & 15);
#pragma unroll
  for (int qi = 0; qi < 4; qi++)
#pragma unroll
    for (int qj = 0; qj < 4; qj++) {
      f32x4 v = acc[qi][qj];
      int row = r0 + qi * 16;
      int col = c0 + qj * 16;
#pragma unroll
      for (int e = 0; e < 4; e++) Y[(size_t)(row + e) * F + col] = v[e];
    }
}

// ---------------------------------------------------------------------------
// Per-node adaptive GEMM over split inputs (unchanged).
// ---------------------------------------------------------------------------
template <int CIN, int COT, int ZR>
__global__ __launch_bounds__(256) void node_gemm(
    const float* __restrict__ xp, const float* __restrict__ hp,
    const float* __restrict__ gxp, const float* __restrict__ ghp,
    const float* __restrict__ E, const float* __restrict__ Wp,
    const float* __restrict__ bp, float* __restrict__ outA,
    float* __restrict__ outB, const float* __restrict__ hmul, int toff) {
  constexpr int XC = (CIN == 66) ? 2 : 64;
  constexpr int K2 = 2 * CIN;
  constexpr int K2R = (K2 + 15) & ~15;
  __shared__ float Wn[K2R][64];
  __shared__ float Xs[16][68];
  int n = blockIdx.x;
  int co0 = blockIdx.y * 64;
  float e[DD];
#pragma unroll
  for (int d = 0; d < DD; d++) e[d] = E[n * DD + d];
  for (int idx = threadIdx.x; idx < K2R * 16; idx += 256) {
    int i2 = idx >> 4, o4 = (idx & 15) << 2;
    float4 s = {0.f, 0.f, 0.f, 0.f};
    if (i2 < K2) {
      int kk = (i2 >= CIN) ? 1 : 0;
      int ii = i2 - kk * CIN;
      const float* wp = Wp + ((size_t)kk * CIN + ii) * COT + co0 + o4;
#pragma unroll
      for (int d = 0; d < DD; d++) {
        float4 w = *(const float4*)(wp + (size_t)d * 2 * CIN * COT);
        s.x += e[d] * w.x; s.y += e[d] * w.y; s.z += e[d] * w.z; s.w += e[d] * w.w;
      }
    }
    *(float4*)&Wn[i2][o4] = s;
  }
  __syncthreads();

  int tx = threadIdx.x & 15, ty = threadIdx.x >> 4;
  float acc[4][4] = {{0.f}};
  for (int k0 = 0; k0 < K2R; k0 += 16) {
#pragma unroll
    for (int r = 0; r < 4; r++) {
      int idx = threadIdx.x + r * 256;
      int b = idx >> 4, kq = idx & 15;
      int i2 = k0 + kq;
      float v = 0.f;
      if (i2 < XC)
        v = (CIN == 66) ? xp[(size_t)n * 1536 + toff + b * 2 + i2]
                        : xp[((size_t)n * 64 + b) * 64 + i2];
      else if (i2 < CIN)
        v = hp[((size_t)n * 64 + b) * 64 + (i2 - XC)];
      else if (i2 < CIN + XC)
        v = (CIN == 66) ? gxp[(size_t)n * 1536 + toff + b * 2 + (i2 - CIN)]
                        : gxp[((size_t)n * 64 + b) * 64 + (i2 - CIN)];
      else if (i2 < K2)
        v = ghp[((size_t)n * 64 + b) * 64 + (i2 - CIN - XC)];
      Xs[kq][b] = v;
    }
    __syncthreads();
#pragma unroll
    for (int kq = 0; kq < 16; kq++) {
      float a[4], w[4];
#pragma unroll
      for (int i = 0; i < 4; i++) a[i] = Xs[kq][ty * 4 + i];
#pragma unroll
      for (int j = 0; j < 4; j++) w[j] = Wn[k0 + kq][tx * 4 + j];
#pragma unroll
      for (int i = 0; i < 4; i++)
#pragma unroll
        for (int j = 0; j < 4; j++) acc[i][j] += a[i] * w[j];
    }
    __syncthreads();
  }
  float bias[4];
#pragma unroll
  for (int j = 0; j < 4; j++) {
    int o = co0 + tx * 4 + j;
    float s = 0.f;
#pragma unroll
    for (int d = 0; d < DD; d++) s += e[d] * bp[d * COT + o];
    bias[j] = s;
  }
#pragma unroll
  for (int i = 0; i < 4; i++) {
    int b = ty * 4 + i;
#pragma unroll
    for (int j = 0; j < 4; j++) {
      float v = acc[i][j] + bias[j];
      size_t o = ((size_t)n * 64 + b) * 64 + tx * 4 + j;
      if (ZR) {
        v = 1.f / (1.f + expf(-v));
        if (co0 == 0) outA[o] = v * hmul[o];
        else          outB[o] = v;
      } else {
        outB[o] = tanhf(v);
      }
    }
  }
}

// ---------------------------------------------------------------------------
// elementwise.  h layout [n,b,c] (c fastest).
// ---------------------------------------------------------------------------
__global__ void init_h(const float* __restrict__ init, float* __restrict__ h0,
                       float* __restrict__ h1) {
  int idx = blockIdx.x * 256 + threadIdx.x;  // N*B*64
  int c = idx & 63, b = (idx >> 6) & 63, n = idx >> 12;
  h0[idx] = init[((size_t)(0 * BB + b) * NN + n) * 64 + c];
  h1[idx] = init[((size_t)(1 * BB + b) * NN + n) * 64 + c];
}

__global__ void transpose_all(const float* __restrict__ x, float* __restrict__ XT) {
  int idx = blockIdx.x * 256 + threadIdx.x;  // N*T*B*2  -> XT[n][t][b][i]
  int i = idx & 1, b = (idx >> 1) & 63;
  int rest = idx >> 7;         // n*12+t
  int t = rest % 12, n = rest / 12;
  XT[idx] = x[(((size_t)b * TT + t) * NN + n) * 2 + i];
}

__global__ void upd0(float* __restrict__ h0, const float* __restrict__ rbuf,
                     const float* __restrict__ hc, const float* __restrict__ stx,
                     const float* __restrict__ Wl, const float* __restrict__ bl,
                     const float* __restrict__ ratio, float* __restrict__ x1, int toff) {
  int idx = blockIdx.x * 256 + threadIdx.x;  // N*B*64
  int j = idx & 63, nb = idx >> 6, b = nb & 63, n = nb >> 6;
  float k = 0.5f + 0.5f * ratio[0];
  float r = rbuf[idx];
  float hn = r * h0[idx] + (1.f - r) * hc[idx];
  h0[idx] = hn;
  float s0 = stx[(size_t)n * 1536 + toff + b * 2 + 0];
  float s1 = stx[(size_t)n * 1536 + toff + b * 2 + 1];
  float s = s0 * Wl[j] + s1 * Wl[64 + j] + bl[j];
  x1[idx] = k * hn + (1.f - k) * s;
}

__global__ void upd1(float* __restrict__ h1, const float* __restrict__ rbuf,
                     const float* __restrict__ hc, const float* __restrict__ stx1,
                     const float* __restrict__ ratio, float* __restrict__ out, int t) {
  int idx = blockIdx.x * 256 + threadIdx.x;  // N*B*64
  int j = idx & 63, b = (idx >> 6) & 63, n = idx >> 12;
  float k = 0.5f + 0.5f * ratio[0];
  float r = rbuf[idx];
  float hn = r * h1[idx] + (1.f - r) * hc[idx];
  h1[idx] = hn;
  float v = k * hn + (1.f - k) * stx1[idx];
  out[(((size_t)b * TT + t) * NN + n) * 64 + j] = v;
}

__global__ void write_hidden(const float* __restrict__ h0, const float* __restrict__ h1,
                             float* __restrict__ out_hid) {
  int idx = blockIdx.x * 256 + threadIdx.x;  // 2*B*N*64
  int c = idx & 63, n = (idx >> 6) & 1023, b = (idx >> 16) & 63, l = idx >> 22;
  const float* h = l ? h1 : h0;
  out_hid[idx] = h[((size_t)(n * 64 + b)) * 64 + c];
}

// ---------------------------------------------------------------------------
extern "C" void kernel_launch(void* const* d_in, const int* in_sizes, int n_in,
                              void* d_out, int out_size, void* d_ws, size_t ws_size,
                              hipStream_t stream) {
  const float* x     = (const float*)d_in[0];
  const float* inis  = (const float*)d_in[1];
  const float* E     = (const float*)d_in[2];
  const float* adj   = (const float*)d_in[3];
  const float* ratio = (const float*)d_in[4];
  const float* Wg0   = (const float*)d_in[5];
  const float* bg0   = (const float*)d_in[6];
  const float* Wu0   = (const float*)d_in[7];
  const float* bu0   = (const float*)d_in[8];
  const float* Wg1   = (const float*)d_in[9];
  const float* bg1   = (const float*)d_in[10];
  const float* Wu1   = (const float*)d_in[11];
  const float* bu1   = (const float*)d_in[12];
  const float* Wl    = (const float*)d_in[13];
  const float* bl    = (const float*)d_in[14];
  float* out = (float*)d_out;

  float* ws = (float*)d_ws;
  size_t off = 0;
  auto alloc = [&](size_t nel) { float* p = ws + off; off += nel; return p; };
  const size_t HSZ = (size_t)NN * BB * 64;  // 4,194,304
  float* Abuf  = alloc((size_t)NN * NN);    // A matrix (fp32)
  float* h0    = alloc(HSZ);
  float* h1    = alloc(HSZ);
  float* x1    = alloc(HSZ);
  float* GhX   = alloc(HSZ);                // shared: Gh(t) then Gh1(t)
  float* Gzh   = alloc(HSZ);
  float* Gx1   = alloc(HSZ);
  float* rbuf  = alloc(HSZ);
  float* tmp   = alloc(HSZ);                // z*h, then hc (in place)
  float* XT    = alloc((size_t)NN * TT * BB * 2);
  float* GxAll = alloc((size_t)NN * TT * BB * 2);
  float* stxAll= alloc((size_t)NN * TT * BB * 2);
  // bf16 hi/lo splits of A and adj: 1024*1024 ushorts = 512K floats each
  unsigned short* Ahi = (unsigned short*)alloc((size_t)NN * NN / 2);
  unsigned short* Alo = (unsigned short*)alloc((size_t)NN * NN / 2);
  unsigned short* Jhi = (unsigned short*)alloc((size_t)NN * NN / 2);
  unsigned short* Jlo = (unsigned short*)alloc((size_t)NN * NN / 2);
  // transposed bf16 hi/lo X buffers: [4096][1024] ushorts = 2M floats each
  const size_t XTSZ = (size_t)4096 * NN / 2;
  unsigned short* XtAh = (unsigned short*)alloc(XTSZ);
  unsigned short* XtAl = (unsigned short*)alloc(XTSZ);
  unsigned short* XtBh = (unsigned short*)alloc(XTSZ);
  unsigned short* XtBl = (unsigned short*)alloc(XTSZ);
  // stx1 lives in the out-hidden tail (overwritten by write_hidden at the end)
  float* stx1 = out + (size_t)BB * TT * NN * 64;

  const int EW = 16384;  // N*B*64 / 256
  build_A<<<NN, 256, 0, stream>>>(E, Abuf);
  split_bf16<<<512, 256, 0, stream>>>(Abuf, Ahi, Alo);
  split_bf16<<<512, 256, 0, stream>>>(adj, Jhi, Jlo);
  init_h<<<EW, 256, 0, stream>>>(inis, h0, h1);
  transpose_all<<<6144, 256, 0, stream>>>(x, XT);
  // batched input convs for all t:  GxAll = A@XT, stxAll = adj@XT  (F=1536)
  txsplit<<<dim3(12, 16), 256, 0, stream>>>(XT, XtAh, XtAl, 1536);
  gemm_mfma<<<dim3(12, 8, 2), 256, 0, stream>>>(
      Ahi, Alo, XtAh, XtAl, GxAll, Jhi, Jlo, XtAh, XtAl, stxAll, 1536);
  // Gh(0) = A @ h0_init
  txsplit<<<dim3(32, 16), 256, 0, stream>>>(h0, XtAh, XtAl, 4096);
  gemm_mfma<<<dim3(32, 8, 1), 256, 0, stream>>>(
      Ahi, Alo, XtAh, XtAl, GhX, nullptr, nullptr, nullptr, nullptr, nullptr, 4096);

  for (int t = 0; t < TT; t++) {
    int toff = t * 128;
    // ---- layer 0 ----
    node_gemm<66, 128, 1><<<dim3(NN, 2), 256, 0, stream>>>(
        XT, h0, GxAll, GhX, E, Wg0, bg0, tmp, rbuf, h0, toff);
    txsplit<<<dim3(32, 16), 256, 0, stream>>>(tmp, XtAh, XtAl, 4096);
    txsplit<<<dim3(32, 16), 256, 0, stream>>>(h1, XtBh, XtBl, 4096);
    gemm_mfma<<<dim3(32, 8, 2), 256, 0, stream>>>(
        Ahi, Alo, XtAh, XtAl, Gzh, Ahi, Alo, XtBh, XtBl, GhX, 4096);
    node_gemm<66, 64, 0><<<dim3(NN, 1), 256, 0, stream>>>(
        XT, tmp, GxAll, Gzh, E, Wu0, bu0, nullptr, tmp, nullptr, toff);
    upd0<<<EW, 256, 0, stream>>>(h0, rbuf, tmp, stxAll, Wl, bl, ratio, x1, toff);
    // ---- layer 1 ----
    txsplit<<<dim3(32, 16), 256, 0, stream>>>(x1, XtAh, XtAl, 4096);
    gemm_mfma<<<dim3(32, 8, 2), 256, 0, stream>>>(
        Ahi, Alo, XtAh, XtAl, Gx1, Jhi, Jlo, XtAh, XtAl, stx1, 4096);
    node_gemm<128, 128, 1><<<dim3(NN, 2), 256, 0, stream>>>(
        x1, h1, Gx1, GhX, E, Wg1, bg1, tmp, rbuf, h1, 0);
    txsplit<<<dim3(32, 16), 256, 0, stream>>>(tmp, XtAh, XtAl, 4096);
    if (t < TT - 1) {
      txsplit<<<dim3(32, 16), 256, 0, stream>>>(h0, XtBh, XtBl, 4096);
      gemm_mfma<<<dim3(32, 8, 2), 256, 0, stream>>>(
          Ahi, Alo, XtAh, XtAl, Gzh, Ahi, Alo, XtBh, XtBl, GhX, 4096);
    } else {
      gemm_mfma<<<dim3(32, 8, 1), 256, 0, stream>>>(
          Ahi, Alo, XtAh, XtAl, Gzh, nullptr, nullptr, nullptr, nullptr, nullptr, 4096);
    }
    node_gemm<128, 64, 0><<<dim3(NN, 1), 256, 0, stream>>>(
        x1, tmp, Gx1, Gzh, E, Wu1, bu1, nullptr, tmp, nullptr, 0);
    upd1<<<EW, 256, 0, stream>>>(h1, rbuf, tmp, stx1, ratio, out, t);
  }
  write_hidden<<<32768, 256, 0, stream>>>(h0, h1, out + (size_t)BB * TT * NN * 64);
}